// Round 1
// baseline (10.497 us; speedup 1.0000x reference)
//
#include <hip/hip_runtime.h>
#include <math.h>

#define FM_H 500
#define FM_W 440
#define ALPHA 0.25f

__device__ __forceinline__ float focal_f(float p) {
    float q = 1.0f - p;
    return -logf(p) * ALPHA * q * q;
}

__device__ __forceinline__ float smooth_l1(float x) {
    float ax = fabsf(x);
    return ax < 1.0f ? 0.5f * x * x : ax - 0.5f;
}

__global__ __launch_bounds__(256) void ppl_kernel(
    const int*   __restrict__ reg_t,   // (B, NB, 2)  [xi, yi]
    const int*   __restrict__ bg_t,    // (B, NBG, 3) [_, x, y]
    const float* __restrict__ gt,      // (B, NB, 4)
    const float* __restrict__ loc,     // (B, 2, 3, H, W)
    const float* __restrict__ size_,   // (B, 2, 3, H, W)
    const float* __restrict__ clf,     // (B, 2, 3, H, W)
    const float* __restrict__ anchor_wh, // (2,)
    float* __restrict__ out,
    int B, int NB, int NBG)
{
    const int tid   = threadIdx.x;
    const int plane = FM_H * FM_W;
    const int per_b = 2 * 3 * plane;   // stride for batch dim of loc/size/clf

    float aw0 = anchor_wh[0], aw1 = anchor_wh[1];
    float inv_da = 1.0f / sqrtf(aw0 * aw0 + aw1 * aw1);

    float bg_sum = 0.f, car_sum = 0.f;
    float sdx = 0.f, sdy = 0.f, sdw = 0.f, sdl = 0.f;

    // ---- background focal: gather clf[b,0,0,y,x] over (B, NBG) ----
    const int nbg_tot = B * NBG;
    for (int i = tid; i < nbg_tot; i += 256) {
        int b = i / NBG;
        const int* t = bg_t + i * 3;
        int x = t[1], y = t[2];
        float p = clf[b * per_b + y * FM_W + x];
        bg_sum += focal_f(p);
    }

    // ---- car / localization terms over (B, NB) ----
    const int nb_tot = B * NB;
    for (int i = tid; i < nb_tot; i += 256) {
        int b = i / NB;
        const int* t = reg_t + i * 2;
        int xi = t[0], yi = t[1];
        bool valid = (xi < FM_W) && (yi < FM_H);
        int xc = min(max(xi, 0), FM_W - 1);
        int yc = min(max(yi, 0), FM_H - 1);
        int base = b * per_b;
        int off  = yc * FM_W + xc;

        const float* g = gt + i * 4;
        float g0 = g[0], g1 = g[1], g2 = g[2], g3 = g[3];
        float w_gt = g3 - g1;
        float l_gt = g2 - g0;
        float x_gt = g0 + 0.5f * w_gt;
        float y_gt = g1 - 0.5f * l_gt;

        float dx = 0.f, dy = 0.f, dw = 0.f, dl = 0.f;
        if (valid) {
            float x_pred = loc[base + off];
            float y_pred = loc[base + plane + off];
            dx = (x_gt - x_pred) * inv_da;
            dy = (y_gt - y_pred) * inv_da;
            float sw = fabsf(size_[base + off]);
            float sl = fabsf(size_[base + plane + off]);
            if (w_gt != 0.f) dw = logf(w_gt / sw);
            if (l_gt != 0.f) dl = logf(l_gt / sl);
            float p_car = clf[base + plane + off];
            car_sum += focal_f(p_car);
        }
        sdx += smooth_l1(dx);
        sdy += smooth_l1(dy);
        sdw += smooth_l1(dw);
        sdl += smooth_l1(dl);
    }

    // ---- block tree reduction of the 6 partial sums ----
    __shared__ float red[6][256];
    red[0][tid] = bg_sum;
    red[1][tid] = car_sum;
    red[2][tid] = sdx;
    red[3][tid] = sdy;
    red[4][tid] = sdw;
    red[5][tid] = sdl;
    __syncthreads();
    for (int s = 128; s > 0; s >>= 1) {
        if (tid < s) {
            #pragma unroll
            for (int k = 0; k < 6; ++k) red[k][tid] += red[k][tid + s];
        }
        __syncthreads();
    }

    if (tid == 0) {
        float bg_loss  = red[0][0] / (float)nbg_tot;
        float car_loss = red[1][0] / (float)nb_tot;
        float loc_loss = (red[2][0] + red[3][0] + red[4][0] + red[5][0]) / (float)nb_tot;
        out[0] = 2.0f * loc_loss + (bg_loss + car_loss);   // BETA_LOC=2, BETA_CLS=1
    }
}

extern "C" void kernel_launch(void* const* d_in, const int* in_sizes, int n_in,
                              void* d_out, int out_size, void* d_ws, size_t ws_size,
                              hipStream_t stream) {
    const int*   reg_t     = (const int*)d_in[0];
    const int*   bg_t      = (const int*)d_in[1];
    const float* gt        = (const float*)d_in[2];
    const float* loc       = (const float*)d_in[3];
    const float* size_     = (const float*)d_in[4];
    const float* clf       = (const float*)d_in[5];
    const float* anchor_wh = (const float*)d_in[9];
    float* out = (float*)d_out;

    // Derive B, NB, NBG from flat sizes: loc is (B,2,3,500,440)
    const int plane = FM_H * FM_W;
    int B   = in_sizes[3] / (2 * 3 * plane);
    int NB  = in_sizes[0] / (2 * B);
    int NBG = in_sizes[1] / (3 * B);

    ppl_kernel<<<1, 256, 0, stream>>>(reg_t, bg_t, gt, loc, size_, clf,
                                      anchor_wh, out, B, NB, NBG);
}

// Round 2
// 9.620 us; speedup vs baseline: 1.0911x; 1.0911x over previous
//
#include <hip/hip_runtime.h>
#include <math.h>

#define FM_H 500
#define FM_W 440
#define ALPHA 0.25f
#define BLK 1024

__device__ __forceinline__ float focal_f(float p) {
    float q = 1.0f - p;
    return -logf(p) * ALPHA * q * q;
}

__device__ __forceinline__ float smooth_l1(float x) {
    float ax = fabsf(x);
    return ax < 1.0f ? 0.5f * x * x : ax - 0.5f;
}

__global__ __launch_bounds__(BLK) void ppl_kernel(
    const int*   __restrict__ reg_t,     // (B, NB, 2)  [xi, yi]
    const int*   __restrict__ bg_t,      // (B, NBG, 3) [_, x, y]
    const float* __restrict__ gt,        // (B, NB, 4)
    const float* __restrict__ loc,       // (B, 2, 3, H, W)
    const float* __restrict__ size_,     // (B, 2, 3, H, W)
    const float* __restrict__ clf,       // (B, 2, 3, H, W)
    const float* __restrict__ anchor_wh, // (2,)
    float* __restrict__ out,
    int B, int NB, int NBG)
{
    const int tid   = threadIdx.x;
    const int plane = FM_H * FM_W;
    const int per_b = 2 * 3 * plane;

    const int nbg_tot = B * NBG;
    const int nb_tot  = B * NB;

    // acc: 0=bg, 1=car, 2=dx, 3=dy, 4=dw, 5=dl
    float acc[6] = {0.f, 0.f, 0.f, 0.f, 0.f, 0.f};

    // ---- background focal: one element per thread (grid-stride for safety) ----
    for (int i = tid; i < nbg_tot; i += BLK) {
        int b = i / NBG;
        const int* t = bg_t + i * 3;
        int x = t[1], y = t[2];
        float p = clf[b * per_b + y * FM_W + x];
        acc[0] += focal_f(p);
    }

    // ---- car / localization: one element per thread ----
    for (int i = tid; i < nb_tot; i += BLK) {
        int b = i / NB;
        const int* t = reg_t + i * 2;
        int xi = t[0], yi = t[1];
        bool valid = (xi < FM_W) && (yi < FM_H);
        int xc = min(max(xi, 0), FM_W - 1);
        int yc = min(max(yi, 0), FM_H - 1);
        int base = b * per_b;
        int off  = yc * FM_W + xc;

        const float* g = gt + i * 4;
        float g0 = g[0], g1 = g[1], g2 = g[2], g3 = g[3];
        float w_gt = g3 - g1;
        float l_gt = g2 - g0;
        float x_gt = g0 + 0.5f * w_gt;
        float y_gt = g1 - 0.5f * l_gt;

        float aw0 = anchor_wh[0], aw1 = anchor_wh[1];
        float inv_da = 1.0f / sqrtf(aw0 * aw0 + aw1 * aw1);

        float dx = 0.f, dy = 0.f, dw = 0.f, dl = 0.f;
        if (valid) {
            float x_pred = loc[base + off];
            float y_pred = loc[base + plane + off];
            dx = (x_gt - x_pred) * inv_da;
            dy = (y_gt - y_pred) * inv_da;
            float sw = fabsf(size_[base + off]);
            float sl = fabsf(size_[base + plane + off]);
            if (w_gt != 0.f) dw = logf(w_gt / sw);
            if (l_gt != 0.f) dl = logf(l_gt / sl);
            float p_car = clf[base + plane + off];
            acc[1] += focal_f(p_car);
        }
        acc[2] += smooth_l1(dx);
        acc[3] += smooth_l1(dy);
        acc[4] += smooth_l1(dw);
        acc[5] += smooth_l1(dl);
    }

    // ---- wave-level butterfly reduce (64 lanes) ----
    #pragma unroll
    for (int k = 0; k < 6; ++k) {
        #pragma unroll
        for (int m = 32; m > 0; m >>= 1)
            acc[k] += __shfl_xor(acc[k], m, 64);
    }

    // ---- cross-wave: 16 waves -> wave 0 ----
    __shared__ float red[16][6];
    const int wave = tid >> 6;
    const int lane = tid & 63;
    if (lane == 0) {
        #pragma unroll
        for (int k = 0; k < 6; ++k) red[wave][k] = acc[k];
    }
    __syncthreads();

    if (tid < 64) {
        float v[6];
        #pragma unroll
        for (int k = 0; k < 6; ++k) v[k] = (lane < 16) ? red[lane][k] : 0.f;
        #pragma unroll
        for (int k = 0; k < 6; ++k) {
            #pragma unroll
            for (int m = 8; m > 0; m >>= 1)
                v[k] += __shfl_xor(v[k], m, 64);
        }
        if (lane == 0) {
            float bg_loss  = v[0] / (float)nbg_tot;
            float car_loss = v[1] / (float)nb_tot;
            float loc_loss = (v[2] + v[3] + v[4] + v[5]) / (float)nb_tot;
            out[0] = 2.0f * loc_loss + (bg_loss + car_loss); // BETA_LOC=2, BETA_CLS=1
        }
    }
}

extern "C" void kernel_launch(void* const* d_in, const int* in_sizes, int n_in,
                              void* d_out, int out_size, void* d_ws, size_t ws_size,
                              hipStream_t stream) {
    const int*   reg_t     = (const int*)d_in[0];
    const int*   bg_t      = (const int*)d_in[1];
    const float* gt        = (const float*)d_in[2];
    const float* loc       = (const float*)d_in[3];
    const float* size_     = (const float*)d_in[4];
    const float* clf       = (const float*)d_in[5];
    const float* anchor_wh = (const float*)d_in[9];
    float* out = (float*)d_out;

    const int plane = FM_H * FM_W;
    int B   = in_sizes[3] / (2 * 3 * plane);
    int NB  = in_sizes[0] / (2 * B);
    int NBG = in_sizes[1] / (3 * B);

    ppl_kernel<<<1, BLK, 0, stream>>>(reg_t, bg_t, gt, loc, size_, clf,
                                      anchor_wh, out, B, NB, NBG);
}